// Round 5
// baseline (3206.371 us; speedup 1.0000x reference)
//
#include <hip/hip_runtime.h>

#define LAYERS 6
#define NH 16
#define DIM 1024
#define VOCAB 32000
#define SEQ 2048
#define NBATCH 2
#define HEADD 64
#define NROW (NBATCH*SEQ)   // 4096
#define FF 4096
#define QKVS 3072
#define LN_EPS 1e-5f

typedef unsigned short bfu;  // bf16 bits
typedef __attribute__((ext_vector_type(8))) short s16x8;
typedef __attribute__((ext_vector_type(4))) float f32x4;

__device__ __forceinline__ float bf2f(bfu u) { return __uint_as_float(((unsigned)u) << 16); }
__device__ __forceinline__ bfu f2bf(float x) {
  unsigned u = __float_as_uint(x);
  return (bfu)((u + 0x7fffu + ((u >> 16) & 1u)) >> 16);  // RNE
}

__device__ __forceinline__ void gload16(const void* g, void* l) {
  __builtin_amdgcn_global_load_lds((const __attribute__((address_space(1))) void*)g,
                                   (__attribute__((address_space(3))) void*)l, 16, 0, 0);
}

__device__ __forceinline__ f32x4 mfma32(s16x8 a, s16x8 b, f32x4 c) {
  return __builtin_amdgcn_mfma_f32_16x16x32_bf16(a, b, c, 0, 0, 0);
}

// ---------------- transpose+convert: out[C][R] (bf16) = in[R][C]^T (fp32) ----------------
__global__ __launch_bounds__(256) void tkernel(const float* __restrict__ in,
                                               bfu* __restrict__ out, int R, int C) {
  __shared__ bfu tile[32][33];
  int tx = threadIdx.x, ty = threadIdx.y;
  int bx = blockIdx.x * 32, by = blockIdx.y * 32;
#pragma unroll
  for (int i = 0; i < 4; ++i)
    tile[ty + i * 8][tx] = f2bf(in[(size_t)(by + ty + i * 8) * C + bx + tx]);
  __syncthreads();
#pragma unroll
  for (int i = 0; i < 4; ++i)
    out[(size_t)(bx + ty + i * 8) * R + by + tx] = tile[tx][ty + i * 8];
}

// batched q/k/v transpose into concatenated qkvT[3072][1024]
__global__ __launch_bounds__(256) void tkernel_qkv(const float* __restrict__ wq,
                                                   const float* __restrict__ wk,
                                                   const float* __restrict__ wv,
                                                   bfu* __restrict__ out) {
  __shared__ bfu tile[32][33];
  const float* in = blockIdx.z == 0 ? wq : blockIdx.z == 1 ? wk : wv;
  bfu* op = out + (size_t)blockIdx.z * DIM * DIM;
  int tx = threadIdx.x, ty = threadIdx.y;
  int bx = blockIdx.x * 32, by = blockIdx.y * 32;
#pragma unroll
  for (int i = 0; i < 4; ++i)
    tile[ty + i * 8][tx] = f2bf(in[(size_t)(by + ty + i * 8) * DIM + bx + tx]);
  __syncthreads();
#pragma unroll
  for (int i = 0; i < 4; ++i)
    op[(size_t)(bx + ty + i * 8) * DIM + by + tx] = tile[tx][ty + i * 8];
}

// ---------------- embedding ----------------
__global__ __launch_bounds__(256) void embed_kernel(const int* __restrict__ idx,
                                                    const float* __restrict__ tok,
                                                    const float* __restrict__ pos,
                                                    float* __restrict__ xf) {
  int row = blockIdx.x;
  int t = row % SEQ;
  int tokid = idx[row];
  int d0 = threadIdx.x * 4;
  float4 tv = *(const float4*)&tok[(size_t)tokid * DIM + d0];
  float4 pv = *(const float4*)&pos[(size_t)t * DIM + d0];
  float4 r;
  r.x = tv.x + pv.x; r.y = tv.y + pv.y; r.z = tv.z + pv.z; r.w = tv.w + pv.w;
  *(float4*)&xf[(size_t)row * DIM + d0] = r;
}

// ---------------- LayerNorm: x fp32 -> h bf16 ----------------
__global__ __launch_bounds__(256) void ln_kernel(const float* __restrict__ xf,
                                                 const float* __restrict__ gw,
                                                 const float* __restrict__ bw,
                                                 bfu* __restrict__ h) {
  int row = blockIdx.x, tid = threadIdx.x;
  const float* xr = xf + (size_t)row * DIM;
  float4 xv4 = ((const float4*)xr)[tid];
  float xv[4] = {xv4.x, xv4.y, xv4.z, xv4.w};
  float s = xv[0] + xv[1] + xv[2] + xv[3];
  float ss = xv[0]*xv[0] + xv[1]*xv[1] + xv[2]*xv[2] + xv[3]*xv[3];
  for (int o = 32; o; o >>= 1) { s += __shfl_xor(s, o); ss += __shfl_xor(ss, o); }
  __shared__ float red[8];
  int wave = tid >> 6;
  if ((tid & 63) == 0) { red[wave * 2] = s; red[wave * 2 + 1] = ss; }
  __syncthreads();
  s  = red[0] + red[2] + red[4] + red[6];
  ss = red[1] + red[3] + red[5] + red[7];
  float mean = s * (1.0f / DIM);
  float var = ss * (1.0f / DIM) - mean * mean;
  float inv = rsqrtf(var + LN_EPS);
  int i0 = tid * 4;
  float4 gv = ((const float4*)gw)[tid];
  float4 bv = ((const float4*)bw)[tid];
  ushort4 hv;
  hv.x = f2bf((xv[0] - mean) * inv * gv.x + bv.x);
  hv.y = f2bf((xv[1] - mean) * inv * gv.y + bv.y);
  hv.z = f2bf((xv[2] - mean) * inv * gv.z + bv.z);
  hv.w = f2bf((xv[3] - mean) * inv * gv.w + bv.w);
  *(ushort4*)(h + (size_t)row * DIM + i0) = hv;
}

// ---------------- GEMM 256x256xBK64, 8 waves, counted-vmcnt ring-2 pipeline ----------------
// C[M,N] = A[M,K] * Bt[N,K]^T.  LDS swizzle: byte ^= (row&7)<<4 within 128B rows.
// MODE 0: bf16 = acc(+bias); 1: bf16 = relu(acc+bias); 2: fp32 = resid+acc+bias; 3: fp32 = acc+bias
template <int MODE>
__global__ __launch_bounds__(512, 2) void gemm256(const bfu* __restrict__ A,
                                                  const bfu* __restrict__ Bt,
                                                  const float* __restrict__ bias,
                                                  const float* resid,
                                                  void* outp,
                                                  int M, int N, int K,
                                                  int colchunk) {
  extern __shared__ char smem[];  // 131072 B: buf{0,1} x (A 32K | B 32K)
  const int tid = threadIdx.x;
  const int lane = tid & 63, w = tid >> 6;
  const int c = lane & 15, g = lane >> 4;

  // XCD swizzle keyed on dispatch-order id (x fastest). nwg % 8 == 0 for all call sites.
  const int gx = gridDim.x, gy = gridDim.y;
  int orig = blockIdx.y * gx + blockIdx.x;
  int cpx = (gx * gy) >> 3;
  int swz = (orig & 7) * cpx + (orig >> 3);
  int bx, by;
  if (colchunk) { bx = swz / gy; by = swz - bx * gy; }   // contiguous N-span per XCD
  else          { by = swz / gx; bx = swz - by * gx; }   // contiguous M-span per XCD
  const int m0 = by * 256, n0 = bx * 256;

  const int wrow = w >> 2, wcol = w & 3;       // wave grid 2(M) x 4(N); wave out = 128x64
  const size_t gstr = (size_t)K * 2;
  const char* Ag = (const char*)A + (size_t)m0 * gstr;
  const char* Bg = (const char*)Bt + (size_t)n0 * gstr;

  // staging: waves 0-3 -> A tile, waves 4-7 -> B tile; 8 gload16/thread per K-tile.
  // gload_lds writes linearly (chunk + lane*16); inverse-swizzle applied to global col.
  const int srow = lane >> 3;                       // row-within-8 of this lane
  const int scol = ((lane & 7) << 4) ^ (srow << 4); // pre-swizzled 16B-granule in 128B row
  const char* gsrc = (w < 4) ? Ag : Bg;
  const int sside = (w < 4) ? 0 : 32768;
  const int schunk0 = (w & 3) * 8;

  auto STAGE = [&](int kt, int buf) {
#pragma unroll
    for (int j = 0; j < 8; ++j) {
      int chunk = schunk0 + j;                 // 32 chunks of 1KB = 8 rows each
      int row = chunk * 8 + srow;
      gload16(gsrc + (size_t)row * gstr + (size_t)kt * 128 + scol,
              smem + buf * 65536 + sside + chunk * 1024);
    }
  };

  const int NT = K >> 6;
  f32x4 acc[8][4] = {};

  STAGE(0, 0);
  STAGE(1, 1);
  asm volatile("s_waitcnt vmcnt(8)" ::: "memory");   // own tile-0 loads done
  __builtin_amdgcn_s_barrier();                      // tile 0 published
  __builtin_amdgcn_sched_barrier(0);

  const int rsw = (c & 7) << 4;
  const int acol0 = (g << 4) ^ rsw;          // k-slice 0 granule (swizzled)
  const int acol1 = (64 + (g << 4)) ^ rsw;   // k-slice 1

  for (int i = 0; i < NT; ++i) {
    const char* ldsA = smem + (i & 1) * 65536;
    const char* ldsB = ldsA + 32768;
    s16x8 a0[8], b0[4], a1[8], b1[4];
#pragma unroll
    for (int mi = 0; mi < 8; ++mi)
      a0[mi] = *(const s16x8*)(ldsA + (wrow * 128 + mi * 16 + c) * 128 + acol0);
#pragma unroll
    for (int ni = 0; ni < 4; ++ni)
      b0[ni] = *(const s16x8*)(ldsB + (wcol * 64 + ni * 16 + c) * 128 + acol0);
    __builtin_amdgcn_s_setprio(1);
#pragma unroll
    for (int mi = 0; mi < 8; ++mi)
#pragma unroll
      for (int ni = 0; ni < 4; ++ni)
        acc[mi][ni] = mfma32(a0[mi], b0[ni], acc[mi][ni]);
    __builtin_amdgcn_s_setprio(0);
#pragma unroll
    for (int mi = 0; mi < 8; ++mi)
      a1[mi] = *(const s16x8*)(ldsA + (wrow * 128 + mi * 16 + c) * 128 + acol1);
#pragma unroll
    for (int ni = 0; ni < 4; ++ni)
      b1[ni] = *(const s16x8*)(ldsB + (wcol * 64 + ni * 16 + c) * 128 + acol1);
    asm volatile("s_waitcnt lgkmcnt(0)" ::: "memory");  // my reads of buf[i&1] complete
    __builtin_amdgcn_sched_barrier(0);
    __builtin_amdgcn_s_barrier();                       // ALL waves done with buf[i&1]
    __builtin_amdgcn_sched_barrier(0);
    if (i + 2 < NT) STAGE(i + 2, i & 1);                // overwrite now-free buffer
    __builtin_amdgcn_s_setprio(1);
#pragma unroll
    for (int mi = 0; mi < 8; ++mi)
#pragma unroll
      for (int ni = 0; ni < 4; ++ni)
        acc[mi][ni] = mfma32(a1[mi], b1[ni], acc[mi][ni]);
    __builtin_amdgcn_s_setprio(0);
    if (i < NT - 2) {
      asm volatile("s_waitcnt vmcnt(8)" ::: "memory");  // tile i+1 loads done (i+2 in flight)
      __builtin_amdgcn_s_barrier();                     // publish tile i+1
      __builtin_amdgcn_sched_barrier(0);
    } else if (i == NT - 2) {
      asm volatile("s_waitcnt vmcnt(0)" ::: "memory");
      __builtin_amdgcn_s_barrier();
      __builtin_amdgcn_sched_barrier(0);
    }
  }

#pragma unroll
  for (int mi = 0; mi < 8; ++mi) {
#pragma unroll
    for (int ni = 0; ni < 4; ++ni) {
      int col = n0 + wcol * 64 + ni * 16 + c;
      float bv = bias ? bias[col] : 0.0f;
#pragma unroll
      for (int jj = 0; jj < 4; ++jj) {
        int row = m0 + wrow * 128 + mi * 16 + g * 4 + jj;
        float val = acc[mi][ni][jj] + bv;
        size_t oi = (size_t)row * N + col;
        if (MODE == 1) val = fmaxf(val, 0.0f);
        if (MODE == 2)      ((float*)outp)[oi] = resid[oi] + val;
        else if (MODE == 3) ((float*)outp)[oi] = val;
        else                ((bfu*)outp)[oi] = f2bf(val);
      }
    }
  }
}

// ---------------- flash attention: 1 wave per (16-row q-tile, head, batch) ----------------
__global__ __launch_bounds__(64) void attn_kernel(const bfu* __restrict__ qkv,
                                                  bfu* __restrict__ o) {
  __shared__ __align__(16) bfu Plds[16 * 32];
  __shared__ __align__(16) bfu Vs[32 * 64];
  const int lane = threadIdx.x;
  const int c = lane & 15, g = lane >> 4;
  const int qt = blockIdx.x, hh = blockIdx.y, b = blockIdx.z;
  const int q0 = qt * 16;
  const float SENT = -1e30f;

  const size_t rowb = (size_t)b * SEQ;
  const size_t qbase = (rowb + q0 + c) * QKVS + hh * HEADD + g * 8;
  s16x8 qf0 = *(const s16x8*)&qkv[qbase];
  s16x8 qf1 = *(const s16x8*)&qkv[qbase + 32];
  const char* vch = (const char*)(qkv + 2048 + rowb * QKVS + hh * HEADD);

  f32x4 oacc[4] = {};
  float mrun = SENT, lrun = 0.0f;

  const int nkt = (q0 >> 5) + 1;
  for (int kt = 0; kt < nkt; ++kt) {
    const int k0 = kt * 32;
#pragma unroll
    for (int i = 0; i < 4; ++i) {
      int flat = i * 1024 + lane * 16;
      int r = flat >> 7, cb = flat & 127;
      gload16(vch + (size_t)(k0 + r) * (QKVS * 2) + cb, (char*)Vs + i * 1024);
    }
    const size_t kb0 = (rowb + k0 + c) * QKVS + 1024 + hh * HEADD + g * 8;
    const size_t kb1 = kb0 + (size_t)16 * QKVS;
    s16x8 kf00 = *(const s16x8*)&qkv[kb0];
    s16x8 kf01 = *(const s16x8*)&qkv[kb0 + 32];
    s16x8 kf10 = *(const s16x8*)&qkv[kb1];
    s16x8 kf11 = *(const s16x8*)&qkv[kb1 + 32];
    f32x4 s0 = {}, s1 = {};
    s0 = mfma32(kf00, qf0, s0); s0 = mfma32(kf01, qf1, s0);
    s1 = mfma32(kf10, qf0, s1); s1 = mfma32(kf11, qf1, s1);

    float sv[8];
#pragma unroll
    for (int jj = 0; jj < 4; ++jj) {
      int ka = k0 + g * 4 + jj, kb = ka + 16;
      sv[jj]     = (ka <= q0 + c) ? s0[jj] * 0.125f : SENT;
      sv[4 + jj] = (kb <= q0 + c) ? s1[jj] * 0.125f : SENT;
    }
    float tmax = sv[0];
#pragma unroll
    for (int i = 1; i < 8; ++i) tmax = fmaxf(tmax, sv[i]);
    tmax = fmaxf(tmax, __shfl_xor(tmax, 16));
    tmax = fmaxf(tmax, __shfl_xor(tmax, 32));
    float mnew = fmaxf(mrun, tmax);
    float alpha = __expf(mrun - mnew);
    float p[8], psum = 0.0f;
#pragma unroll
    for (int i = 0; i < 8; ++i) { p[i] = __expf(sv[i] - mnew); psum += p[i]; }
    psum += __shfl_xor(psum, 16);
    psum += __shfl_xor(psum, 32);
    lrun = lrun * alpha + psum;
    mrun = mnew;

    ushort4 w0; w0.x = f2bf(p[0]); w0.y = f2bf(p[1]); w0.z = f2bf(p[2]); w0.w = f2bf(p[3]);
    ushort4 w1; w1.x = f2bf(p[4]); w1.y = f2bf(p[5]); w1.z = f2bf(p[6]); w1.w = f2bf(p[7]);
    *(ushort4*)&Plds[c * 32 + g * 4] = w0;
    *(ushort4*)&Plds[c * 32 + 16 + g * 4] = w1;
    __syncthreads();

    float aq[4];
#pragma unroll
    for (int jj = 0; jj < 4; ++jj) aq[jj] = __shfl(alpha, g * 4 + jj);

    ushort4 ra = *(const ushort4*)&Plds[c * 32 + g * 8];
    ushort4 rb = *(const ushort4*)&Plds[c * 32 + g * 8 + 4];
    s16x8 pa = {(short)ra.x, (short)ra.y, (short)ra.z, (short)ra.w,
                (short)rb.x, (short)rb.y, (short)rb.z, (short)rb.w};
    __syncthreads();

    asm volatile("s_waitcnt vmcnt(0)" ::: "memory");
#pragma unroll
    for (int dg = 0; dg < 4; ++dg) {
      s16x8 vf;
#pragma unroll
      for (int j = 0; j < 8; ++j)
        vf[j] = (short)Vs[(g * 8 + j) * 64 + dg * 16 + c];
#pragma unroll
      for (int jj = 0; jj < 4; ++jj) oacc[dg][jj] *= aq[jj];
      oacc[dg] = mfma32(pa, vf, oacc[dg]);
    }
  }

  float lq[4];
#pragma unroll
  for (int jj = 0; jj < 4; ++jj) lq[jj] = __shfl(lrun, g * 4 + jj);
#pragma unroll
  for (int dg = 0; dg < 4; ++dg)
#pragma unroll
    for (int jj = 0; jj < 4; ++jj) {
      size_t oi = (size_t)(rowb + q0 + g * 4 + jj) * DIM + hh * HEADD + dg * 16 + c;
      o[oi] = f2bf(oacc[dg][jj] / lq[jj]);
    }
}

// ---------------- per-row NLL (fp32 logits) ----------------
__global__ __launch_bounds__(256) void nll_kernel(const float* __restrict__ logits,
                                                  const int* __restrict__ tgt,
                                                  float* __restrict__ nll) {
  int row = blockIdx.x;
  const float* lp = logits + (size_t)row * VOCAB;
  float m = -3.0e38f, s = 0.0f;
  for (int i = threadIdx.x * 4; i < VOCAB; i += 1024) {
    float4 u = *(const float4*)(lp + i);
    float x[4] = {u.x, u.y, u.z, u.w};
#pragma unroll
    for (int j = 0; j < 4; ++j) {
      float nm = fmaxf(m, x[j]);
      s = s * __expf(m - nm) + __expf(x[j] - nm);
      m = nm;
    }
  }
  for (int off = 32; off; off >>= 1) {
    float om = __shfl_xor(m, off), os = __shfl_xor(s, off);
    float nm = fmaxf(m, om);
    s = s * __expf(m - nm) + os * __expf(om - nm);
    m = nm;
  }
  __shared__ float rm[4], rsh[4];
  int wave = threadIdx.x >> 6;
  if ((threadIdx.x & 63) == 0) { rm[wave] = m; rsh[wave] = s; }
  __syncthreads();
  if (threadIdx.x == 0) {
    float M = rm[0], S = rsh[0];
    for (int w = 1; w < 4; ++w) {
      float nm = fmaxf(M, rm[w]);
      S = S * __expf(M - nm) + rsh[w] * __expf(rm[w] - nm);
      M = nm;
    }
    nll[row] = (M + __logf(S)) - lp[tgt[row]];
  }
}

__global__ __launch_bounds__(256) void loss_kernel(const float* __restrict__ nll,
                                                   float* __restrict__ out) {
  float s = 0.0f;
  for (int i = threadIdx.x; i < NROW; i += 256) s += nll[i];
  for (int off = 32; off; off >>= 1) s += __shfl_xor(s, off);
  __shared__ float r[4];
  int wave = threadIdx.x >> 6;
  if ((threadIdx.x & 63) == 0) r[wave] = s;
  __syncthreads();
  if (threadIdx.x == 0) out[(size_t)NROW * VOCAB] = (r[0] + r[1] + r[2] + r[3]) * (1.0f / NROW);
}

// ---------------- host ----------------
extern "C" void kernel_launch(void* const* d_in, const int* in_sizes, int n_in,
                              void* d_out, int out_size, void* d_ws, size_t ws_size,
                              hipStream_t stream) {
  (void)in_sizes; (void)n_in; (void)out_size;
  const int* idx       = (const int*)d_in[0];
  const int* targets   = (const int*)d_in[1];
  const float* tok_emb = (const float*)d_in[2];
  const float* pos_emb = (const float*)d_in[3];
  const float* wq      = (const float*)d_in[4];
  const float* wk      = (const float*)d_in[5];
  const float* wv      = (const float*)d_in[6];
  const float* w_proj  = (const float*)d_in[7];
  const float* b_proj  = (const float*)d_in[8];
  const float* w_fc1   = (const float*)d_in[9];
  const float* b_fc1   = (const float*)d_in[10];
  const float* w_fc2   = (const float*)d_in[11];
  const float* b_fc2   = (const float*)d_in[12];
  const float* ln1_g   = (const float*)d_in[13];
  const float* ln1_b   = (const float*)d_in[14];
  const float* ln2_g   = (const float*)d_in[15];
  const float* ln2_b   = (const float*)d_in[16];
  const float* lnf_g   = (const float*)d_in[17];
  const float* lnf_b   = (const float*)d_in[18];
  const float* w_head  = (const float*)d_in[19];
  const float* b_head  = (const float*)d_in[20];

  char* ws = (char*)d_ws;
  size_t off = 0;
  auto alloc = [&](size_t bytes) {
    char* p = ws + off;
    off += (bytes + 255) & ~(size_t)255;
    return p;
  };
  float* xf  = (float*)alloc((size_t)NROW * DIM * 4);
  bfu* hbuf  = (bfu*)alloc((size_t)NROW * DIM * 2);
  bfu* qkvb  = (bfu*)alloc((size_t)NROW * QKVS * 2);
  bfu* ob    = (bfu*)alloc((size_t)NROW * DIM * 2);
  bfu* ub    = (bfu*)alloc((size_t)NROW * FF * 2);
  bfu* qkvT  = (bfu*)alloc((size_t)QKVS * DIM * 2);
  bfu* wpT   = (bfu*)alloc((size_t)DIM * DIM * 2);
  bfu* f1T   = (bfu*)alloc((size_t)DIM * FF * 2);
  bfu* f2T   = (bfu*)alloc((size_t)DIM * FF * 2);
  bfu* hT    = (bfu*)alloc((size_t)DIM * VOCAB * 2);
  float* nll = (float*)alloc((size_t)NROW * 4);
  if (off > ws_size) return;

  const size_t LDSB = 131072;
  dim3 tb(32, 8);
  tkernel<<<dim3(VOCAB / 32, DIM / 32), tb, 0, stream>>>(w_head, hT, DIM, VOCAB);
  embed_kernel<<<NROW, 256, 0, stream>>>(idx, tok_emb, pos_emb, xf);

  float* logits = (float*)d_out;
  for (int l = 0; l < LAYERS; ++l) {
    const size_t wo = (size_t)l * DIM * DIM, fo = (size_t)l * DIM * FF;
    tkernel_qkv<<<dim3(DIM / 32, DIM / 32, 3), tb, 0, stream>>>(wq + wo, wk + wo, wv + wo, qkvT);
    tkernel<<<dim3(DIM / 32, DIM / 32), tb, 0, stream>>>(w_proj + wo, wpT, DIM, DIM);
    tkernel<<<dim3(FF / 32, DIM / 32), tb, 0, stream>>>(w_fc1 + fo, f1T, DIM, FF);
    tkernel<<<dim3(DIM / 32, FF / 32), tb, 0, stream>>>(w_fc2 + fo, f2T, FF, DIM);

    ln_kernel<<<NROW, 256, 0, stream>>>(xf, ln1_g + l * DIM, ln1_b + l * DIM, hbuf);
    gemm256<0><<<dim3(QKVS / 256, NROW / 256), 512, LDSB, stream>>>(
        hbuf, qkvT, nullptr, nullptr, qkvb, NROW, QKVS, DIM, 0);
    attn_kernel<<<dim3(SEQ / 16, NH, NBATCH), 64, 0, stream>>>(qkvb, ob);
    gemm256<2><<<dim3(DIM / 256, NROW / 256), 512, LDSB, stream>>>(
        ob, wpT, b_proj + l * DIM, xf, xf, NROW, DIM, DIM, 0);
    ln_kernel<<<NROW, 256, 0, stream>>>(xf, ln2_g + l * DIM, ln2_b + l * DIM, hbuf);
    gemm256<1><<<dim3(FF / 256, NROW / 256), 512, LDSB, stream>>>(
        hbuf, f1T, b_fc1 + l * FF, nullptr, ub, NROW, FF, DIM, 0);
    gemm256<2><<<dim3(DIM / 256, NROW / 256), 512, LDSB, stream>>>(
        ub, f2T, b_fc2 + l * DIM, xf, xf, NROW, DIM, FF, 0);
  }

  ln_kernel<<<NROW, 256, 0, stream>>>(xf, lnf_g, lnf_b, hbuf);
  gemm256<3><<<dim3(VOCAB / 256, NROW / 256), 512, LDSB, stream>>>(
      hbuf, hT, b_head, nullptr, logits, NROW, VOCAB, DIM, 1);
  nll_kernel<<<NROW, 256, 0, stream>>>(logits, targets, nll);
  loss_kernel<<<1, 256, 0, stream>>>(nll, logits);
}

// Round 6
// 2856.726 us; speedup vs baseline: 1.1224x; 1.1224x over previous
//
#include <hip/hip_runtime.h>

#define LAYERS 6
#define NH 16
#define DIM 1024
#define VOCAB 32000
#define SEQ 2048
#define NBATCH 2
#define HEADD 64
#define NROW (NBATCH*SEQ)   // 4096
#define FF 4096
#define QKVS 3072
#define LN_EPS 1e-5f

typedef unsigned short bfu;  // bf16 bits
typedef __attribute__((ext_vector_type(8))) short s16x8;
typedef __attribute__((ext_vector_type(4))) float f32x4;

__device__ __forceinline__ float bf2f(bfu u) { return __uint_as_float(((unsigned)u) << 16); }
__device__ __forceinline__ bfu f2bf(float x) {
  unsigned u = __float_as_uint(x);
  return (bfu)((u + 0x7fffu + ((u >> 16) & 1u)) >> 16);  // RNE
}

__device__ __forceinline__ void gload16(const void* g, void* l) {
  __builtin_amdgcn_global_load_lds((const __attribute__((address_space(1))) void*)g,
                                   (__attribute__((address_space(3))) void*)l, 16, 0, 0);
}

__device__ __forceinline__ f32x4 mfma32(s16x8 a, s16x8 b, f32x4 c) {
  return __builtin_amdgcn_mfma_f32_16x16x32_bf16(a, b, c, 0, 0, 0);
}

// ---------------- transpose+convert: out[C][R] (bf16) = in[R][C]^T (fp32) ----------------
__global__ __launch_bounds__(256) void tkernel(const float* __restrict__ in,
                                               bfu* __restrict__ out, int R, int C) {
  __shared__ bfu tile[32][33];
  int tx = threadIdx.x, ty = threadIdx.y;
  int bx = blockIdx.x * 32, by = blockIdx.y * 32;
#pragma unroll
  for (int i = 0; i < 4; ++i)
    tile[ty + i * 8][tx] = f2bf(in[(size_t)(by + ty + i * 8) * C + bx + tx]);
  __syncthreads();
#pragma unroll
  for (int i = 0; i < 4; ++i)
    out[(size_t)(bx + ty + i * 8) * R + by + tx] = tile[tx][ty + i * 8];
}

// batched q/k/v transpose into concatenated qkvT[3072][1024]
__global__ __launch_bounds__(256) void tkernel_qkv(const float* __restrict__ wq,
                                                   const float* __restrict__ wk,
                                                   const float* __restrict__ wv,
                                                   bfu* __restrict__ out) {
  __shared__ bfu tile[32][33];
  const float* in = blockIdx.z == 0 ? wq : blockIdx.z == 1 ? wk : wv;
  bfu* op = out + (size_t)blockIdx.z * DIM * DIM;
  int tx = threadIdx.x, ty = threadIdx.y;
  int bx = blockIdx.x * 32, by = blockIdx.y * 32;
#pragma unroll
  for (int i = 0; i < 4; ++i)
    tile[ty + i * 8][tx] = f2bf(in[(size_t)(by + ty + i * 8) * DIM + bx + tx]);
  __syncthreads();
#pragma unroll
  for (int i = 0; i < 4; ++i)
    op[(size_t)(bx + ty + i * 8) * DIM + by + tx] = tile[tx][ty + i * 8];
}

// ---------------- embedding ----------------
__global__ __launch_bounds__(256) void embed_kernel(const int* __restrict__ idx,
                                                    const float* __restrict__ tok,
                                                    const float* __restrict__ pos,
                                                    float* __restrict__ xf) {
  int row = blockIdx.x;
  int t = row % SEQ;
  int tokid = idx[row];
  int d0 = threadIdx.x * 4;
  float4 tv = *(const float4*)&tok[(size_t)tokid * DIM + d0];
  float4 pv = *(const float4*)&pos[(size_t)t * DIM + d0];
  float4 r;
  r.x = tv.x + pv.x; r.y = tv.y + pv.y; r.z = tv.z + pv.z; r.w = tv.w + pv.w;
  *(float4*)&xf[(size_t)row * DIM + d0] = r;
}

// ---------------- LayerNorm: x fp32 -> h bf16 ----------------
__global__ __launch_bounds__(256) void ln_kernel(const float* __restrict__ xf,
                                                 const float* __restrict__ gw,
                                                 const float* __restrict__ bw,
                                                 bfu* __restrict__ h) {
  int row = blockIdx.x, tid = threadIdx.x;
  const float* xr = xf + (size_t)row * DIM;
  float4 xv4 = ((const float4*)xr)[tid];
  float xv[4] = {xv4.x, xv4.y, xv4.z, xv4.w};
  float s = xv[0] + xv[1] + xv[2] + xv[3];
  float ss = xv[0]*xv[0] + xv[1]*xv[1] + xv[2]*xv[2] + xv[3]*xv[3];
  for (int o = 32; o; o >>= 1) { s += __shfl_xor(s, o); ss += __shfl_xor(ss, o); }
  __shared__ float red[8];
  int wave = tid >> 6;
  if ((tid & 63) == 0) { red[wave * 2] = s; red[wave * 2 + 1] = ss; }
  __syncthreads();
  s  = red[0] + red[2] + red[4] + red[6];
  ss = red[1] + red[3] + red[5] + red[7];
  float mean = s * (1.0f / DIM);
  float var = ss * (1.0f / DIM) - mean * mean;
  float inv = rsqrtf(var + LN_EPS);
  int i0 = tid * 4;
  float4 gv = ((const float4*)gw)[tid];
  float4 bv = ((const float4*)bw)[tid];
  ushort4 hv;
  hv.x = f2bf((xv[0] - mean) * inv * gv.x + bv.x);
  hv.y = f2bf((xv[1] - mean) * inv * gv.y + bv.y);
  hv.z = f2bf((xv[2] - mean) * inv * gv.z + bv.z);
  hv.w = f2bf((xv[3] - mean) * inv * gv.w + bv.w);
  *(ushort4*)(h + (size_t)row * DIM + i0) = hv;
}

// ---------------- GEMM 128x128xBK32 (proven): for small-N layer GEMMs ----------------
// MODE 0: bf16 = acc(+bias); 1: bf16 = relu(acc+bias); 2: fp32 = resid+acc+bias; 3: fp32 = acc+bias
template <int MODE>
__global__ __launch_bounds__(256) void gemm_bt(const bfu* __restrict__ A,
                                               const bfu* __restrict__ Bt,
                                               const float* __restrict__ bias,
                                               const float* resid,
                                               void* outp,
                                               int M, int N, int K) {
  __shared__ __align__(16) bfu As[128 * 32];
  __shared__ __align__(16) bfu Bs[128 * 32];
  const int tid = threadIdx.x;
  const int lane = tid & 63, wave = tid >> 6;
  const int c = lane & 15, g = lane >> 4;

  const int gx = gridDim.x, gy = gridDim.y;
  int orig = blockIdx.y * gx + blockIdx.x;           // dispatch order (x fastest)
  int cpx = (gx * gy) >> 3;
  int swz = (orig & 7) * cpx + (orig >> 3);
  int by = swz / gx, bx = swz - by * gx;             // contiguous M-span per XCD

  const int m0 = by * 128, n0 = bx * 128;
  const int wm = (wave & 1) * 64, wn = (wave >> 1) * 64;
  f32x4 acc[4][4] = {};
  const char* Ac = (const char*)A;
  const char* Bc = (const char*)Bt;
  const size_t stride = (size_t)K * 2;

  for (int kt = 0; kt < K; kt += 32) {
    __syncthreads();
#pragma unroll
    for (int i = 0; i < 2; ++i) {
      int fb = wave * 1024 + i * 4096;
      int flat = fb + lane * 16;
      int row = flat >> 6, colb = flat & 63;
      gload16(Ac + (size_t)(m0 + row) * stride + (size_t)kt * 2 + colb, (char*)As + fb);
      gload16(Bc + (size_t)(n0 + row) * stride + (size_t)kt * 2 + colb, (char*)Bs + fb);
    }
    asm volatile("s_waitcnt vmcnt(0)" ::: "memory");
    __syncthreads();
    s16x8 af[4], bfr[4];
#pragma unroll
    for (int mi = 0; mi < 4; ++mi)
      af[mi] = *(const s16x8*)&As[(wm + mi * 16 + c) * 32 + g * 8];
#pragma unroll
    for (int ni = 0; ni < 4; ++ni)
      bfr[ni] = *(const s16x8*)&Bs[(wn + ni * 16 + c) * 32 + g * 8];
#pragma unroll
    for (int mi = 0; mi < 4; ++mi)
#pragma unroll
      for (int ni = 0; ni < 4; ++ni)
        acc[mi][ni] = mfma32(af[mi], bfr[ni], acc[mi][ni]);
  }

#pragma unroll
  for (int mi = 0; mi < 4; ++mi) {
#pragma unroll
    for (int ni = 0; ni < 4; ++ni) {
      int col = n0 + wn + ni * 16 + c;
      float bv = bias ? bias[col] : 0.0f;
#pragma unroll
      for (int jj = 0; jj < 4; ++jj) {
        int row = m0 + wm + mi * 16 + g * 4 + jj;
        float val = acc[mi][ni][jj] + bv;
        size_t oi = (size_t)row * N + col;
        if (MODE == 1) val = fmaxf(val, 0.0f);
        if (MODE == 2)      ((float*)outp)[oi] = resid[oi] + val;
        else if (MODE == 3) ((float*)outp)[oi] = val;
        else                ((bfu*)outp)[oi] = f2bf(val);
      }
    }
  }
}

// ---------------- GEMM 256x256xBK64, 16 waves (64x64/wave), ring-2 counted-vmcnt ----------------
template <int MODE>
__global__ __launch_bounds__(1024) void gemm1024(const bfu* __restrict__ A,
                                                 const bfu* __restrict__ Bt,
                                                 const float* __restrict__ bias,
                                                 const float* resid,
                                                 void* outp,
                                                 int M, int N, int K,
                                                 int colchunk) {
  extern __shared__ char smem[];  // 131072: buf{0,1} x (A 32K | B 32K)
  const int tid = threadIdx.x;
  const int lane = tid & 63, w = tid >> 6;     // 16 waves
  const int c = lane & 15, g = lane >> 4;

  const int gx = gridDim.x, gy = gridDim.y;
  int orig = blockIdx.y * gx + blockIdx.x;     // dispatch order
  int cpx = (gx * gy) >> 3;
  int swz = (orig & 7) * cpx + (orig >> 3);
  int bx, by;
  if (colchunk) { bx = swz / gy; by = swz - bx * gy; }
  else          { by = swz / gx; bx = swz - by * gx; }
  const int m0 = by * 256, n0 = bx * 256;

  const int wrow = w >> 2, wcol = w & 3;       // 4x4 wave grid; wave out 64x64
  const size_t gstr = (size_t)K * 2;
  const char* Ag = (const char*)A + (size_t)m0 * gstr;
  const char* Bg = (const char*)Bt + (size_t)n0 * gstr;

  // staging: 2048 16B-granules per tile side; thread t stages granules t and t+1024
  // LDS dest linear (wave-uniform base + lane*16); global col pre-swizzled (^ row&7)
  int srow0 = tid >> 3, scg0 = (tid & 7) ^ (srow0 & 7);
  int srow1 = (tid + 1024) >> 3, scg1 = (tid & 7) ^ (srow1 & 7);
  const size_t ga0 = (size_t)srow0 * gstr + scg0 * 16;
  const size_t ga1 = (size_t)srow1 * gstr + scg1 * 16;

  auto STAGE = [&](int kt, int buf) {
    char* base = smem + buf * 65536;
    size_t ko = (size_t)kt * 128;
    gload16(Ag + ga0 + ko, base + w * 1024);
    gload16(Ag + ga1 + ko, base + 16384 + w * 1024);
    gload16(Bg + ga0 + ko, base + 32768 + w * 1024);
    gload16(Bg + ga1 + ko, base + 49152 + w * 1024);
  };

  const int NT = K >> 6;
  f32x4 acc[4][4] = {};

  STAGE(0, 0);
  STAGE(1, 1);
  asm volatile("s_waitcnt vmcnt(4)" ::: "memory");
  __builtin_amdgcn_s_barrier();
  __builtin_amdgcn_sched_barrier(0);

  const int rsw = (c & 7) << 4;
  const int off0 = (g * 16) ^ rsw;          // k-slice 0
  const int off1 = (64 + g * 16) ^ rsw;     // k-slice 1

  for (int i = 0; i < NT; ++i) {
    const char* ldsA = smem + (i & 1) * 65536 + (wrow * 64 + c) * 128;
    const char* ldsB = smem + (i & 1) * 65536 + 32768 + (wcol * 64 + c) * 128;
    s16x8 a[4], b[4];
    // ---- k-slice 0 ----
#pragma unroll
    for (int mi = 0; mi < 4; ++mi) a[mi] = *(const s16x8*)(ldsA + mi * 2048 + off0);
#pragma unroll
    for (int ni = 0; ni < 4; ++ni) b[ni] = *(const s16x8*)(ldsB + ni * 2048 + off0);
    __builtin_amdgcn_s_setprio(1);
#pragma unroll
    for (int mi = 0; mi < 4; ++mi)
#pragma unroll
      for (int ni = 0; ni < 4; ++ni)
        acc[mi][ni] = mfma32(a[mi], b[ni], acc[mi][ni]);
    __builtin_amdgcn_s_setprio(0);
    // ---- k-slice 1 ----
#pragma unroll
    for (int mi = 0; mi < 4; ++mi) a[mi] = *(const s16x8*)(ldsA + mi * 2048 + off1);
#pragma unroll
    for (int ni = 0; ni < 4; ++ni) b[ni] = *(const s16x8*)(ldsB + ni * 2048 + off1);
    asm volatile("s_waitcnt lgkmcnt(0)" ::: "memory");  // my reads of buf[i&1] done
    __builtin_amdgcn_sched_barrier(0);
    __builtin_amdgcn_s_barrier();                       // all waves done with buf[i&1]
    __builtin_amdgcn_sched_barrier(0);
    if (i + 2 < NT) STAGE(i + 2, i & 1);                // refill now-free buffer
    __builtin_amdgcn_s_setprio(1);
#pragma unroll
    for (int mi = 0; mi < 4; ++mi)
#pragma unroll
      for (int ni = 0; ni < 4; ++ni)
        acc[mi][ni] = mfma32(a[mi], b[ni], acc[mi][ni]);
    __builtin_amdgcn_s_setprio(0);
    if (i < NT - 2) {
      asm volatile("s_waitcnt vmcnt(4)" ::: "memory");  // tile i+1 ready (i+2 in flight)
      __builtin_amdgcn_s_barrier();
      __builtin_amdgcn_sched_barrier(0);
    } else if (i == NT - 2) {
      asm volatile("s_waitcnt vmcnt(0)" ::: "memory");
      __builtin_amdgcn_s_barrier();
      __builtin_amdgcn_sched_barrier(0);
    }
  }

#pragma unroll
  for (int mi = 0; mi < 4; ++mi) {
#pragma unroll
    for (int ni = 0; ni < 4; ++ni) {
      int col = n0 + wcol * 64 + ni * 16 + c;
      float bv = bias ? bias[col] : 0.0f;
#pragma unroll
      for (int jj = 0; jj < 4; ++jj) {
        int row = m0 + wrow * 64 + mi * 16 + g * 4 + jj;
        float val = acc[mi][ni][jj] + bv;
        size_t oi = (size_t)row * N + col;
        if (MODE == 1) val = fmaxf(val, 0.0f);
        if (MODE == 2)      ((float*)outp)[oi] = resid[oi] + val;
        else if (MODE == 3) ((float*)outp)[oi] = val;
        else                ((bfu*)outp)[oi] = f2bf(val);
      }
    }
  }
}

// ---------------- flash attention: 4 waves/block, 64 q-rows/block, shared K/V LDS ----------------
__global__ __launch_bounds__(256) void attn_kernel(const bfu* __restrict__ qkv,
                                                   bfu* __restrict__ o) {
  __shared__ __align__(16) bfu Ks[32 * 64];       // swizzled
  __shared__ __align__(16) bfu Vs[32 * 64];       // linear
  __shared__ __align__(16) bfu Plds[4 * 16 * 32]; // per-wave P roundtrip
  const int tid = threadIdx.x;
  const int lane = tid & 63, w = tid >> 6;
  const int c = lane & 15, g = lane >> 4;
  const int qt = blockIdx.x, hh = blockIdx.y, b = blockIdx.z;
  const int q0 = qt * 64 + w * 16;                // wave's 16 q-rows
  const float SENT = -1e30f;
  const size_t rowb = (size_t)b * SEQ;

  const size_t qbase = (rowb + q0 + c) * QKVS + hh * HEADD + g * 8;
  s16x8 qf0 = *(const s16x8*)&qkv[qbase];
  s16x8 qf1 = *(const s16x8*)&qkv[qbase + 32];

  bfu* Pw = Plds + w * 512;
  const int srow = tid >> 3;                      // staging row 0..31
  const int kcg = (tid & 7) ^ (srow & 7);         // swizzled granule (K)
  const int vcg = tid & 7;                        // linear granule (V)
  const bfu* Kg = qkv + 1024 + hh * HEADD;
  const bfu* Vg = qkv + 2048 + hh * HEADD;
  const int rsw = (c & 7) << 4;
  const int koff0 = (g * 16) ^ rsw;
  const int koff1 = (64 + g * 16) ^ rsw;

  f32x4 oacc[4] = {};
  float mrun = SENT, lrun = 0.0f;

  const int nkt = 2 * qt + 2;                     // covers k <= qt*64+63
  for (int kt = 0; kt < nkt; ++kt) {
    const int k0 = kt * 32;
    __syncthreads();                              // all waves done with prev K/V tile
    gload16(Kg + (rowb + k0 + srow) * QKVS + kcg * 8, (char*)Ks + w * 1024);
    gload16(Vg + (rowb + k0 + srow) * QKVS + vcg * 8, (char*)Vs + w * 1024);
    asm volatile("s_waitcnt vmcnt(0)" ::: "memory");
    __syncthreads();                              // K/V tile published

    const char* Kb = (const char*)Ks;
    s16x8 kf00 = *(const s16x8*)(Kb + c * 128 + koff0);
    s16x8 kf01 = *(const s16x8*)(Kb + c * 128 + koff1);
    s16x8 kf10 = *(const s16x8*)(Kb + (16 + c) * 128 + koff0);
    s16x8 kf11 = *(const s16x8*)(Kb + (16 + c) * 128 + koff1);
    f32x4 s0 = {}, s1 = {};
    s0 = mfma32(kf00, qf0, s0); s0 = mfma32(kf01, qf1, s0);  // S[q0+c][k0+g*4+jj]
    s1 = mfma32(kf10, qf0, s1); s1 = mfma32(kf11, qf1, s1);  // S[q0+c][k0+16+g*4+jj]

    float sv[8];
#pragma unroll
    for (int jj = 0; jj < 4; ++jj) {
      int ka = k0 + g * 4 + jj, kb = ka + 16;
      sv[jj]     = (ka <= q0 + c) ? s0[jj] * 0.125f : SENT;
      sv[4 + jj] = (kb <= q0 + c) ? s1[jj] * 0.125f : SENT;
    }
    float tmax = sv[0];
#pragma unroll
    for (int i = 1; i < 8; ++i) tmax = fmaxf(tmax, sv[i]);
    tmax = fmaxf(tmax, __shfl_xor(tmax, 16));
    tmax = fmaxf(tmax, __shfl_xor(tmax, 32));
    float mnew = fmaxf(mrun, tmax);
    float alpha = __expf(mrun - mnew);
    float p[8], psum = 0.0f;
#pragma unroll
    for (int i = 0; i < 8; ++i) { p[i] = __expf(sv[i] - mnew); psum += p[i]; }
    psum += __shfl_xor(psum, 16);
    psum += __shfl_xor(psum, 32);
    lrun = lrun * alpha + psum;
    mrun = mnew;

    ushort4 w0; w0.x = f2bf(p[0]); w0.y = f2bf(p[1]); w0.z = f2bf(p[2]); w0.w = f2bf(p[3]);
    ushort4 w1; w1.x = f2bf(p[4]); w1.y = f2bf(p[5]); w1.z = f2bf(p[6]); w1.w = f2bf(p[7]);
    *(ushort4*)&Pw[c * 32 + g * 4] = w0;
    *(ushort4*)&Pw[c * 32 + 16 + g * 4] = w1;
    __syncthreads();                              // own-region write->read ordering

    float aq[4];
#pragma unroll
    for (int jj = 0; jj < 4; ++jj) aq[jj] = __shfl(alpha, g * 4 + jj);

    ushort4 ra = *(const ushort4*)&Pw[c * 32 + g * 8];
    ushort4 rb = *(const ushort4*)&Pw[c * 32 + g * 8 + 4];
    s16x8 pa = {(short)ra.x, (short)ra.y, (short)ra.z, (short)ra.w,
                (short)rb.x, (short)rb.y, (short)rb.z, (short)rb.w};

#pragma unroll
    for (int dg = 0; dg < 4; ++dg) {
      s16x8 vf;
#pragma unroll
      for (int j = 0; j < 8; ++j)
        vf[j] = (short)Vs[(g * 8 + j) * 64 + dg * 16 + c];
#pragma unroll
      for (int jj = 0; jj < 4; ++jj) oacc[dg][jj] *= aq[jj];
      oacc[dg] = mfma32(pa, vf, oacc[dg]);
    }
  }

  float lq[4];
#pragma unroll
  for (int jj = 0; jj < 4; ++jj) lq[jj] = __shfl(lrun, g * 4 + jj);
#pragma unroll
  for (int dg = 0; dg < 4; ++dg)
#pragma unroll
    for (int jj = 0; jj < 4; ++jj) {
      size_t oi = (size_t)(rowb + q0 + g * 4 + jj) * DIM + hh * HEADD + dg * 16 + c;
      o[oi] = f2bf(oacc[dg][jj] / lq[jj]);
    }
}

// ---------------- per-row NLL (fp32 logits) ----------------
__global__ __launch_bounds__(256) void nll_kernel(const float* __restrict__ logits,
                                                  const int* __restrict__ tgt,
                                                  float* __restrict__ nll) {
  int row = blockIdx.x;
  const float* lp = logits + (size_t)row * VOCAB;
  float m = -3.0e38f, s = 0.0f;
  for (int i = threadIdx.x * 4; i < VOCAB; i += 1024) {
    float4 u = *(const float4*)(lp + i);
    float x[4] = {u.x, u.y, u.z, u.w};
#pragma unroll
    for (int j = 0; j < 4; ++j) {
      float nm = fmaxf(m, x[j]);
      s = s * __expf(m - nm) + __expf(x[j] - nm);
      m = nm;
    }
  }
  for (int off = 32; off; off >>= 1) {
    float om = __shfl_xor(m, off), os = __shfl_xor(s, off);
    float nm = fmaxf(m, om);
    s = s * __expf(m - nm) + os * __expf(om - nm);
    m = nm;
  }
  __shared__ float rm[4], rsh[4];
  int wave = threadIdx.x >> 6;
  if ((threadIdx.x & 63) == 0) { rm[wave] = m; rsh[wave] = s; }
  __syncthreads();
  if (threadIdx.x == 0) {
    float M = rm[0], S = rsh[0];
    for (int w = 1; w < 4; ++w) {
      float nm = fmaxf(M, rm[w]);
      S = S * __expf(M - nm) + rsh[w] * __expf(rm[w] - nm);
      M = nm;
    }
    nll[row] = (M + __logf(S)) - lp[tgt[row]];
  }
}

__global__ __launch_bounds__(256) void loss_kernel(const float* __restrict__ nll,
                                                   float* __restrict__ out) {
  float s = 0.0f;
  for (int i = threadIdx.x; i < NROW; i += 256) s += nll[i];
  for (int off = 32; off; off >>= 1) s += __shfl_xor(s, off);
  __shared__ float r[4];
  int wave = threadIdx.x >> 6;
  if ((threadIdx.x & 63) == 0) r[wave] = s;
  __syncthreads();
  if (threadIdx.x == 0) out[(size_t)NROW * VOCAB] = (r[0] + r[1] + r[2] + r[3]) * (1.0f / NROW);
}

// ---------------- host ----------------
extern "C" void kernel_launch(void* const* d_in, const int* in_sizes, int n_in,
                              void* d_out, int out_size, void* d_ws, size_t ws_size,
                              hipStream_t stream) {
  (void)in_sizes; (void)n_in; (void)out_size;
  const int* idx       = (const int*)d_in[0];
  const int* targets   = (const int*)d_in[1];
  const float* tok_emb = (const float*)d_in[2];
  const float* pos_emb = (const float*)d_in[3];
  const float* wq      = (const float*)d_in[4];
  const float* wk      = (const float*)d_in[5];
  const float* wv      = (const float*)d_in[6];
  const float* w_proj  = (const float*)d_in[7];
  const float* b_proj  = (const float*)d_in[8];
  const float* w_fc1   = (const float*)d_in[9];
  const float* b_fc1   = (const float*)d_in[10];
  const float* w_fc2   = (const float*)d_in[11];
  const float* b_fc2   = (const float*)d_in[12];
  const float* ln1_g   = (const float*)d_in[13];
  const float* ln1_b   = (const float*)d_in[14];
  const float* ln2_g   = (const float*)d_in[15];
  const float* ln2_b   = (const float*)d_in[16];
  const float* lnf_g   = (const float*)d_in[17];
  const float* lnf_b   = (const float*)d_in[18];
  const float* w_head  = (const float*)d_in[19];
  const float* b_head  = (const float*)d_in[20];

  char* ws = (char*)d_ws;
  size_t off = 0;
  auto alloc = [&](size_t bytes) {
    char* p = ws + off;
    off += (bytes + 255) & ~(size_t)255;
    return p;
  };
  float* xf  = (float*)alloc((size_t)NROW * DIM * 4);
  bfu* hbuf  = (bfu*)alloc((size_t)NROW * DIM * 2);
  bfu* qkvb  = (bfu*)alloc((size_t)NROW * QKVS * 2);
  bfu* ob    = (bfu*)alloc((size_t)NROW * DIM * 2);
  bfu* ub    = (bfu*)alloc((size_t)NROW * FF * 2);
  bfu* qkvT  = (bfu*)alloc((size_t)QKVS * DIM * 2);
  bfu* wpT   = (bfu*)alloc((size_t)DIM * DIM * 2);
  bfu* f1T   = (bfu*)alloc((size_t)DIM * FF * 2);
  bfu* f2T   = (bfu*)alloc((size_t)DIM * FF * 2);
  bfu* hT    = (bfu*)alloc((size_t)DIM * VOCAB * 2);
  float* nll = (float*)alloc((size_t)NROW * 4);
  if (off > ws_size) return;

  const size_t LDSB = 131072;
  dim3 tb(32, 8);
  tkernel<<<dim3(VOCAB / 32, DIM / 32), tb, 0, stream>>>(w_head, hT, DIM, VOCAB);
  embed_kernel<<<NROW, 256, 0, stream>>>(idx, tok_emb, pos_emb, xf);

  float* logits = (float*)d_out;
  for (int l = 0; l < LAYERS; ++l) {
    const size_t wo = (size_t)l * DIM * DIM, fo = (size_t)l * DIM * FF;
    tkernel_qkv<<<dim3(DIM / 32, DIM / 32, 3), tb, 0, stream>>>(wq + wo, wk + wo, wv + wo, qkvT);
    tkernel<<<dim3(DIM / 32, DIM / 32), tb, 0, stream>>>(w_proj + wo, wpT, DIM, DIM);
    tkernel<<<dim3(FF / 32, DIM / 32), tb, 0, stream>>>(w_fc1 + fo, f1T, DIM, FF);
    tkernel<<<dim3(DIM / 32, FF / 32), tb, 0, stream>>>(w_fc2 + fo, f2T, FF, DIM);

    ln_kernel<<<NROW, 256, 0, stream>>>(xf, ln1_g + l * DIM, ln1_b + l * DIM, hbuf);
    gemm_bt<0><<<dim3(QKVS / 128, NROW / 128), 256, 0, stream>>>(
        hbuf, qkvT, nullptr, nullptr, qkvb, NROW, QKVS, DIM);
    attn_kernel<<<dim3(SEQ / 64, NH, NBATCH), 256, 0, stream>>>(qkvb, ob);
    gemm_bt<2><<<dim3(DIM / 128, NROW / 128), 256, 0, stream>>>(
        ob, wpT, b_proj + l * DIM, xf, xf, NROW, DIM, DIM);
    ln_kernel<<<NROW, 256, 0, stream>>>(xf, ln2_g + l * DIM, ln2_b + l * DIM, hbuf);
    gemm1024<1><<<dim3(FF / 256, NROW / 256), 1024, LDSB, stream>>>(
        hbuf, f1T, b_fc1 + l * FF, nullptr, ub, NROW, FF, DIM, 0);
    gemm_bt<2><<<dim3(DIM / 128, NROW / 128), 256, 0, stream>>>(
        ub, f2T, b_fc2 + l * DIM, xf, xf, NROW, DIM, FF);
  }

  ln_kernel<<<NROW, 256, 0, stream>>>(xf, lnf_g, lnf_b, hbuf);
  gemm1024<3><<<dim3(VOCAB / 256, NROW / 256), 1024, LDSB, stream>>>(
      hbuf, hT, b_head, nullptr, logits, NROW, VOCAB, DIM, 1);
  nll_kernel<<<NROW, 256, 0, stream>>>(logits, targets, nll);
  loss_kernel<<<1, 256, 0, stream>>>(nll, logits);
}